// Round 10
// baseline (502.082 us; speedup 1.0000x reference)
//
#include <hip/hip_runtime.h>
#include <math.h>

constexpr int NE  = 16;   // experts
constexpr int NG  = 4;    // groups
constexpr int NSL = 8;    // k-slices = waves per block (K1)
constexpr int KS  = 8;    // k per step (w-chunk 8x16 f64 in LDS)
constexpr int TPB1 = 128; // tokens per K1 block (2 per lane)

__global__ __launch_bounds__(256)
void w_transpose_kernel(const float* __restrict__ w, float* __restrict__ wt,
                        int dim, int n) {
    int id = blockIdx.x * 256 + threadIdx.x;
    if (id < n) {
        int k = id / NE;
        int e = id - k * NE;
        wt[id] = w[(size_t)e * dim + k];   // [k][e] fp32
    }
}

// K1: fp64 partial dot products. 8 waves/block, each wave one 512-dim slice
// of the block's 128 tokens (2 per lane). No barriers, no cross-wave traffic.
__global__ __launch_bounds__(512, 4)
void k1_partials(const float* __restrict__ x,
                 const float* __restrict__ wt,
                 double* __restrict__ P,          // [NSL][n_tokens][NE]
                 int n_tokens, int dim)
{
    __shared__ double wbuf[NSL][KS][NE];          // 8 KB

    const int tid  = threadIdx.x;
    const int uwid = __builtin_amdgcn_readfirstlane(tid >> 6);
    const int lane = tid & 63;
    const int slice = dim / NSL;                  // 512
    const int nst  = slice / KS;                  // 64
    const long tokA = (long)blockIdx.x * TPB1 + lane;
    const long tokB = tokA + 64;

    const float* xA = x + tokA * (size_t)dim + (size_t)uwid * slice;
    const float* xB = x + tokB * (size_t)dim + (size_t)uwid * slice;
    const float* wp = wt + (size_t)uwid * slice * NE;

    double accA[NE], accB[NE];
#pragma unroll
    for (int e = 0; e < NE; ++e) { accA[e] = 0.0; accB[e] = 0.0; }

    // prologue: step-0 x (8 floats per token) + w chunk (2 floats per lane)
    float4 a0 = *(const float4*)(xA + 0), a1 = *(const float4*)(xA + 4);
    float4 b0 = *(const float4*)(xB + 0), b1 = *(const float4*)(xB + 4);
    float2 wreg = *(const float2*)(wp + lane * 2);

    for (int c = 0; c < nst; ++c) {
        // stage w chunk c into LDS as fp64 (convert once; wave-ordered DS)
        {
            double* dst = &wbuf[uwid][0][0] + lane * 2;
            dst[0] = (double)wreg.x;  dst[1] = (double)wreg.y;
        }

        // prefetch step c+1
        float4 na0 = a0, na1 = a1, nb0 = b0, nb1 = b1;
        if (c + 1 < nst) {
            const float* pa = xA + (c + 1) * KS;
            const float* pb = xB + (c + 1) * KS;
            na0 = *(const float4*)(pa + 0);  na1 = *(const float4*)(pa + 4);
            nb0 = *(const float4*)(pb + 0);  nb1 = *(const float4*)(pb + 4);
            wreg = *(const float2*)(wp + (size_t)(c + 1) * KS * NE + lane * 2);
        }

        float fa[KS], fb[KS];
        fa[0]=a0.x; fa[1]=a0.y; fa[2]=a0.z; fa[3]=a0.w;
        fa[4]=a1.x; fa[5]=a1.y; fa[6]=a1.z; fa[7]=a1.w;
        fb[0]=b0.x; fb[1]=b0.y; fb[2]=b0.z; fb[3]=b0.w;
        fb[4]=b1.x; fb[5]=b1.y; fb[6]=b1.z; fb[7]=b1.w;

        // each broadcast double2 read feeds 4 FMAs (2 experts x 2 tokens)
#pragma unroll
        for (int kk = 0; kk < KS; ++kk) {
            double xa_ = (double)fa[kk];
            double xb_ = (double)fb[kk];
#pragma unroll
            for (int ep = 0; ep < NE / 2; ++ep) {
                double2 wv = *(const double2*)&wbuf[uwid][kk][ep * 2];
                accA[ep * 2 + 0] = fma(xa_, wv.x, accA[ep * 2 + 0]);
                accA[ep * 2 + 1] = fma(xa_, wv.y, accA[ep * 2 + 1]);
                accB[ep * 2 + 0] = fma(xb_, wv.x, accB[ep * 2 + 0]);
                accB[ep * 2 + 1] = fma(xb_, wv.y, accB[ep * 2 + 1]);
            }
        }

        a0 = na0; a1 = na1; b0 = nb0; b1 = nb1;
    }

    // write partials: per token 16 contiguous doubles (128 B per lane run)
    double* pA = P + ((size_t)uwid * n_tokens + tokA) * NE;
    double* pB = P + ((size_t)uwid * n_tokens + tokB) * NE;
#pragma unroll
    for (int j = 0; j < NE / 2; ++j) {
        double2 v; v.x = accA[2 * j]; v.y = accA[2 * j + 1];
        *(double2*)(pA + 2 * j) = v;
    }
#pragma unroll
    for (int j = 0; j < NE / 2; ++j) {
        double2 v; v.x = accB[2 * j]; v.y = accB[2 * j + 1];
        *(double2*)(pB + 2 * j) = v;
    }
}

// K2: sum the 8 slice-partials (fixed order) + fp64 epilogue per token.
__global__ __launch_bounds__(256)
void k2_finalize(const double* __restrict__ P,
                 const float* __restrict__ w1b,
                 const float* __restrict__ rbias,
                 float* __restrict__ dout,
                 int n_tokens)
{
    const long t = (long)blockIdx.x * 256 + threadIdx.x;
    if (t >= n_tokens) return;

    double tot[NE];
#pragma unroll
    for (int e = 0; e < NE; ++e) tot[e] = 0.0;
    for (int s = 0; s < NSL; ++s) {
        const double* ps = P + ((size_t)s * n_tokens + t) * NE;
#pragma unroll
        for (int j = 0; j < NE / 2; ++j) {
            double2 v = *(const double2*)(ps + 2 * j);
            tot[2 * j + 0] += v.x;
            tot[2 * j + 1] += v.y;
        }
    }

    double logit[NE];
    double m = -INFINITY;
#pragma unroll
    for (int e = 0; e < NE; ++e) {
        logit[e] = tot[e] + (double)w1b[e];
        m = fmax(m, logit[e]);
    }
    double ssum = 0.0;
    double p[NE];
#pragma unroll
    for (int e = 0; e < NE; ++e) { p[e] = exp(logit[e] - m); ssum += p[e]; }
    double inv = 1.0 / ssum;
    double sc[NE];
#pragma unroll
    for (int e = 0; e < NE; ++e) sc[e] = p[e] * inv + (double)rbias[e];

    double gm[NG];
#pragma unroll
    for (int g = 0; g < NG; ++g) {
        double a = fmax(sc[g * 4 + 0], sc[g * 4 + 1]);
        double b = fmax(sc[g * 4 + 2], sc[g * 4 + 3]);
        gm[g] = fmax(a, b);
    }
    int g1 = 0;
#pragma unroll
    for (int g = 1; g < NG; ++g) if (gm[g] > gm[g1]) g1 = g;
    int g2 = (g1 == 0) ? 1 : 0;
#pragma unroll
    for (int g = 0; g < NG; ++g) if (g != g1 && gm[g] > gm[g2]) g2 = g;

    double v1 = -INFINITY; int i1 = 0;
#pragma unroll
    for (int e = 0; e < NE; ++e) {
        int g = e >> 2;
        bool keep = (g == g1) || (g == g2);
        if (keep && sc[e] > v1) { v1 = sc[e]; i1 = e; }
    }
    double v2 = -INFINITY; int i2 = 0;
#pragma unroll
    for (int e = 0; e < NE; ++e) {
        int g = e >> 2;
        bool keep = ((g == g1) || (g == g2)) && (e != i1);
        if (keep && sc[e] > v2) { v2 = sc[e]; i2 = e; }
    }

    float2 vv; vv.x = (float)v1; vv.y = (float)v2;
    *(float2*)(dout + t * 2) = vv;
    float2 iv; iv.x = (float)i1; iv.y = (float)i2;
    *(float2*)(dout + (long)n_tokens * 2 + t * 2) = iv;
}

// ---------------- fallback (round-9 proven structure, w gathered) -----------
__global__ __launch_bounds__(256)
void router_fallback(const float* __restrict__ x,
                     const float* __restrict__ w1w,
                     const float* __restrict__ w1b,
                     const float* __restrict__ rbias,
                     float* __restrict__ dout,
                     int n_tokens, int dim)
{
    __shared__ double wbuf4[4][16][NE];
    const int tid  = threadIdx.x;
    const int uwid = __builtin_amdgcn_readfirstlane(tid >> 6);
    const int lane = tid & 63;
    const int slice = dim / 4;
    const int nst  = slice / 16;
    const long tokA = (long)blockIdx.x * 128 + lane;
    const long tokB = tokA + 64;
    const float* xA = x + tokA * (size_t)dim + (size_t)uwid * slice;
    const float* xB = x + tokB * (size_t)dim + (size_t)uwid * slice;

    double accA[NE], accB[NE];
#pragma unroll
    for (int e = 0; e < NE; ++e) { accA[e] = 0.0; accB[e] = 0.0; }

    float4 a0 = *(const float4*)(xA + 0), a1 = *(const float4*)(xA + 4);
    float4 a2 = *(const float4*)(xA + 8), a3 = *(const float4*)(xA + 12);
    float4 b0 = *(const float4*)(xB + 0), b1 = *(const float4*)(xB + 4);
    float4 b2 = *(const float4*)(xB + 8), b3 = *(const float4*)(xB + 12);
    float4 wreg;
    {
        const int i0 = lane * 4;
#pragma unroll
        for (int j = 0; j < 4; ++j) {
            int i = i0 + j;
            ((float*)&wreg)[j] = w1w[(size_t)(i & 15) * dim + uwid * slice + (i >> 4)];
        }
    }

    for (int c = 0; c < nst; ++c) {
        {
            double* dst = &wbuf4[uwid][0][0] + lane * 4;
            dst[0] = (double)wreg.x;  dst[1] = (double)wreg.y;
            dst[2] = (double)wreg.z;  dst[3] = (double)wreg.w;
        }
        float4 na0=a0,na1=a1,na2=a2,na3=a3,nb0=b0,nb1=b1,nb2=b2,nb3=b3;
        if (c + 1 < nst) {
            const float* pa = xA + (c + 1) * 16;
            const float* pb = xB + (c + 1) * 16;
            na0 = *(const float4*)(pa + 0);  na1 = *(const float4*)(pa + 4);
            na2 = *(const float4*)(pa + 8);  na3 = *(const float4*)(pa + 12);
            nb0 = *(const float4*)(pb + 0);  nb1 = *(const float4*)(pb + 4);
            nb2 = *(const float4*)(pb + 8);  nb3 = *(const float4*)(pb + 12);
            const int kb = uwid * slice + (c + 1) * 16;
            const int i0 = lane * 4;
#pragma unroll
            for (int j = 0; j < 4; ++j) {
                int i = i0 + j;
                ((float*)&wreg)[j] = w1w[(size_t)(i & 15) * dim + kb + (i >> 4)];
            }
        }
        float fa[16], fb[16];
        fa[0]=a0.x; fa[1]=a0.y; fa[2]=a0.z; fa[3]=a0.w;
        fa[4]=a1.x; fa[5]=a1.y; fa[6]=a1.z; fa[7]=a1.w;
        fa[8]=a2.x; fa[9]=a2.y; fa[10]=a2.z; fa[11]=a2.w;
        fa[12]=a3.x; fa[13]=a3.y; fa[14]=a3.z; fa[15]=a3.w;
        fb[0]=b0.x; fb[1]=b0.y; fb[2]=b0.z; fb[3]=b0.w;
        fb[4]=b1.x; fb[5]=b1.y; fb[6]=b1.z; fb[7]=b1.w;
        fb[8]=b2.x; fb[9]=b2.y; fb[10]=b2.z; fb[11]=b2.w;
        fb[12]=b3.x; fb[13]=b3.y; fb[14]=b3.z; fb[15]=b3.w;
#pragma unroll
        for (int kk = 0; kk < 16; ++kk) {
            double xa_ = (double)fa[kk];
            double xb_ = (double)fb[kk];
#pragma unroll
            for (int ep = 0; ep < NE / 2; ++ep) {
                double2 wv = *(const double2*)&wbuf4[uwid][kk][ep * 2];
                accA[ep*2+0] = fma(xa_, wv.x, accA[ep*2+0]);
                accA[ep*2+1] = fma(xa_, wv.y, accA[ep*2+1]);
                accB[ep*2+0] = fma(xb_, wv.x, accB[ep*2+0]);
                accB[ep*2+1] = fma(xb_, wv.y, accB[ep*2+1]);
            }
        }
        a0=na0; a1=na1; a2=na2; a3=na3;
        b0=nb0; b1=nb1; b2=nb2; b3=nb3;
    }

    __syncthreads();
    __shared__ double red[3][2][64][NE + 1];
    if (uwid != 0) {
#pragma unroll
        for (int e = 0; e < NE; ++e) {
            red[uwid - 1][0][lane][e] = accA[e];
            red[uwid - 1][1][lane][e] = accB[e];
        }
    }
    __syncthreads();
    if (uwid != 0) return;

#pragma unroll
    for (int t = 0; t < 2; ++t) {
        double tot[NE];
#pragma unroll
        for (int e = 0; e < NE; ++e) {
            double a = (t == 0) ? accA[e] : accB[e];
            tot[e] = ((a + red[0][t][lane][e]) + red[1][t][lane][e])
                     + red[2][t][lane][e];
        }
        double logit[NE];
        double m = -INFINITY;
#pragma unroll
        for (int e = 0; e < NE; ++e) {
            logit[e] = tot[e] + (double)w1b[e];
            m = fmax(m, logit[e]);
        }
        double ssum = 0.0, p[NE];
#pragma unroll
        for (int e = 0; e < NE; ++e) { p[e] = exp(logit[e] - m); ssum += p[e]; }
        double inv = 1.0 / ssum, sc[NE];
#pragma unroll
        for (int e = 0; e < NE; ++e) sc[e] = p[e] * inv + (double)rbias[e];
        double gm[NG];
#pragma unroll
        for (int g = 0; g < NG; ++g) {
            double a = fmax(sc[g*4+0], sc[g*4+1]);
            double b = fmax(sc[g*4+2], sc[g*4+3]);
            gm[g] = fmax(a, b);
        }
        int g1 = 0;
#pragma unroll
        for (int g = 1; g < NG; ++g) if (gm[g] > gm[g1]) g1 = g;
        int g2 = (g1 == 0) ? 1 : 0;
#pragma unroll
        for (int g = 0; g < NG; ++g) if (g != g1 && gm[g] > gm[g2]) g2 = g;
        double v1 = -INFINITY; int i1 = 0;
#pragma unroll
        for (int e = 0; e < NE; ++e) {
            int g = e >> 2;
            bool keep = (g == g1) || (g == g2);
            if (keep && sc[e] > v1) { v1 = sc[e]; i1 = e; }
        }
        double v2 = -INFINITY; int i2 = 0;
#pragma unroll
        for (int e = 0; e < NE; ++e) {
            int g = e >> 2;
            bool keep = ((g == g1) || (g == g2)) && (e != i1);
            if (keep && sc[e] > v2) { v2 = sc[e]; i2 = e; }
        }
        long tok = (t == 0) ? tokA : tokB;
        float2 vv; vv.x = (float)v1; vv.y = (float)v2;
        *(float2*)(dout + tok * 2) = vv;
        float2 iv; iv.x = (float)i1; iv.y = (float)i2;
        *(float2*)(dout + (long)n_tokens * 2 + tok * 2) = iv;
    }
}

extern "C" void kernel_launch(void* const* d_in, const int* in_sizes, int n_in,
                              void* d_out, int out_size, void* d_ws, size_t ws_size,
                              hipStream_t stream)
{
    const float* x   = (const float*)d_in[0];
    const float* w1w = (const float*)d_in[1];
    const float* w1b = (const float*)d_in[2];
    const float* rb  = (const float*)d_in[3];
    float* out = (float*)d_out;

    const int ne       = in_sizes[2];            // 16
    const int dim      = in_sizes[1] / ne;       // 4096
    const int n_tokens = in_sizes[0] / dim;      // 65536

    const int nW = dim * ne;                     // 65536 w elements
    const size_t partials_bytes = (size_t)NSL * n_tokens * NE * sizeof(double); // 67 MB
    const size_t need = partials_bytes + (size_t)nW * sizeof(float);

    if (ws_size >= need) {
        double* P  = (double*)d_ws;
        float*  wt = (float*)((char*)d_ws + partials_bytes);
        hipLaunchKernelGGL(w_transpose_kernel, dim3((nW + 255) / 256), dim3(256),
                           0, stream, w1w, wt, dim, nW);
        hipLaunchKernelGGL(k1_partials, dim3(n_tokens / TPB1), dim3(NSL * 64),
                           0, stream, x, wt, P, n_tokens, dim);
        hipLaunchKernelGGL(k2_finalize, dim3((n_tokens + 255) / 256), dim3(256),
                           0, stream, P, w1b, rb, out, n_tokens);
    } else {
        hipLaunchKernelGGL(router_fallback, dim3(n_tokens / 128), dim3(256),
                           0, stream, x, w1w, w1b, rb, out, n_tokens, dim);
    }
}

// Round 11
// 491.468 us; speedup vs baseline: 1.0216x; 1.0216x over previous
//
#include <hip/hip_runtime.h>
#include <math.h>

constexpr int NE  = 16;   // experts
constexpr int NG  = 4;    // groups
constexpr int NSL = 4;    // k-slices = waves per block (K1)
constexpr int KS  = 16;   // k per step
constexpr int TPB = 128;  // tokens per K1 block (2 per lane)
#define MARGIN 1e-3

__global__ __launch_bounds__(256)
void w_transpose_kernel(const float* __restrict__ w, float* __restrict__ wt,
                        int dim, int n) {
    int id = blockIdx.x * 256 + threadIdx.x;
    if (id < n) {
        int k = id / NE;
        int e = id - k * NE;
        wt[id] = w[(size_t)e * dim + k];   // [k][e] fp32
    }
}

struct RouteR { double v1, v2; int i1, i2; double mg, mo, ms; };

// fp64 epilogue from logit totals; also returns ranking margins
__device__ __forceinline__ RouteR route_epilogue(const double* tot,
                                                 const float* w1b,
                                                 const float* rbias)
{
    double logit[NE];
    double m = -INFINITY;
#pragma unroll
    for (int e = 0; e < NE; ++e) {
        logit[e] = tot[e] + (double)w1b[e];
        m = fmax(m, logit[e]);
    }
    double ssum = 0.0, p[NE];
#pragma unroll
    for (int e = 0; e < NE; ++e) { p[e] = exp(logit[e] - m); ssum += p[e]; }
    double inv = 1.0 / ssum, sc[NE];
#pragma unroll
    for (int e = 0; e < NE; ++e) sc[e] = p[e] * inv + (double)rbias[e];

    double gm[NG];
#pragma unroll
    for (int g = 0; g < NG; ++g) {
        double a = fmax(sc[g * 4 + 0], sc[g * 4 + 1]);
        double b = fmax(sc[g * 4 + 2], sc[g * 4 + 3]);
        gm[g] = fmax(a, b);
    }
    int g1 = 0;
#pragma unroll
    for (int g = 1; g < NG; ++g) if (gm[g] > gm[g1]) g1 = g;
    int g2 = (g1 == 0) ? 1 : 0;
#pragma unroll
    for (int g = 0; g < NG; ++g) if (g != g1 && gm[g] > gm[g2]) g2 = g;
    double gm3 = -INFINITY;
#pragma unroll
    for (int g = 0; g < NG; ++g)
        if (g != g1 && g != g2 && gm[g] > gm3) gm3 = gm[g];

    RouteR r;
    r.v1 = -INFINITY; r.i1 = 0;
#pragma unroll
    for (int e = 0; e < NE; ++e) {
        int g = e >> 2;
        bool keep = (g == g1) || (g == g2);
        if (keep && sc[e] > r.v1) { r.v1 = sc[e]; r.i1 = e; }
    }
    r.v2 = -INFINITY; r.i2 = 0;
#pragma unroll
    for (int e = 0; e < NE; ++e) {
        int g = e >> 2;
        bool keep = ((g == g1) || (g == g2)) && (e != r.i1);
        if (keep && sc[e] > r.v2) { r.v2 = sc[e]; r.i2 = e; }
    }
    double v3 = -INFINITY;
#pragma unroll
    for (int e = 0; e < NE; ++e) {
        int g = e >> 2;
        bool keep = ((g == g1) || (g == g2)) && (e != r.i1) && (e != r.i2);
        if (keep && sc[e] > v3) v3 = sc[e];
    }
    r.mg = gm[g2] - gm3;   // group-selection margin (2nd vs 3rd group)
    r.mo = r.v1 - r.v2;    // top1/top2 order margin
    r.ms = r.v2 - v3;      // top2-selection margin
    return r;
}

// K1: fp32 main pass (round-9 skeleton, dtype fp32; flags near-ties)
__global__ __launch_bounds__(256)
void k1_main(const float* __restrict__ x,
             const float* __restrict__ wt,
             const float* __restrict__ w1b,
             const float* __restrict__ rbias,
             float* __restrict__ dout,
             int* __restrict__ fcount,
             int* __restrict__ flist,
             int n_tokens, int dim)
{
    __shared__ float wbuf[NSL][KS][NE];           // 4 KB
    __shared__ float red[NSL - 1][2][64][NE + 1]; // 26112 B

    const int tid  = threadIdx.x;
    const int uwid = __builtin_amdgcn_readfirstlane(tid >> 6);
    const int lane = tid & 63;
    const int slice = dim / NSL;          // 1024
    const int nst  = slice / KS;          // 64
    const long tokA = (long)blockIdx.x * TPB + lane;
    const long tokB = tokA + 64;

    const float* xA = x + tokA * (size_t)dim + (size_t)uwid * slice;
    const float* xB = x + tokB * (size_t)dim + (size_t)uwid * slice;
    const float* wp = wt + (size_t)uwid * slice * NE;

    float accA[NE], accB[NE];
#pragma unroll
    for (int e = 0; e < NE; ++e) { accA[e] = 0.f; accB[e] = 0.f; }

    float4 a0 = *(const float4*)(xA + 0),  a1 = *(const float4*)(xA + 4);
    float4 a2 = *(const float4*)(xA + 8),  a3 = *(const float4*)(xA + 12);
    float4 b0 = *(const float4*)(xB + 0),  b1 = *(const float4*)(xB + 4);
    float4 b2 = *(const float4*)(xB + 8),  b3 = *(const float4*)(xB + 12);
    float4 wreg = *(const float4*)(wp + lane * 4);

    for (int c = 0; c < nst; ++c) {
        // stage w chunk (fp32, 1 KB) into this wave's LDS buffer
        ((float4*)&wbuf[uwid][0][0])[lane] = wreg;

        // prefetch step c+1
        float4 na0 = a0, na1 = a1, na2 = a2, na3 = a3;
        float4 nb0 = b0, nb1 = b1, nb2 = b2, nb3 = b3;
        if (c + 1 < nst) {
            const float* pa = xA + (c + 1) * KS;
            const float* pb = xB + (c + 1) * KS;
            na0 = *(const float4*)(pa + 0);  na1 = *(const float4*)(pa + 4);
            na2 = *(const float4*)(pa + 8);  na3 = *(const float4*)(pa + 12);
            nb0 = *(const float4*)(pb + 0);  nb1 = *(const float4*)(pb + 4);
            nb2 = *(const float4*)(pb + 8);  nb3 = *(const float4*)(pb + 12);
            wreg = *(const float4*)(wp + (size_t)(c + 1) * KS * NE + lane * 4);
        }

        float fa[KS], fb[KS];
        fa[0]=a0.x;  fa[1]=a0.y;  fa[2]=a0.z;  fa[3]=a0.w;
        fa[4]=a1.x;  fa[5]=a1.y;  fa[6]=a1.z;  fa[7]=a1.w;
        fa[8]=a2.x;  fa[9]=a2.y;  fa[10]=a2.z; fa[11]=a2.w;
        fa[12]=a3.x; fa[13]=a3.y; fa[14]=a3.z; fa[15]=a3.w;
        fb[0]=b0.x;  fb[1]=b0.y;  fb[2]=b0.z;  fb[3]=b0.w;
        fb[4]=b1.x;  fb[5]=b1.y;  fb[6]=b1.z;  fb[7]=b1.w;
        fb[8]=b2.x;  fb[9]=b2.y;  fb[10]=b2.z; fb[11]=b2.w;
        fb[12]=b3.x; fb[13]=b3.y; fb[14]=b3.z; fb[15]=b3.w;

        // fp32 FMAs: one broadcast float4 (4 experts) feeds 8 FMAs (2 tokens)
#pragma unroll
        for (int kk = 0; kk < KS; ++kk) {
            float xa_ = fa[kk];
            float xb_ = fb[kk];
#pragma unroll
            for (int eg = 0; eg < 4; ++eg) {
                float4 wv = *(const float4*)&wbuf[uwid][kk][eg * 4];
                accA[eg*4+0] = fmaf(xa_, wv.x, accA[eg*4+0]);
                accA[eg*4+1] = fmaf(xa_, wv.y, accA[eg*4+1]);
                accA[eg*4+2] = fmaf(xa_, wv.z, accA[eg*4+2]);
                accA[eg*4+3] = fmaf(xa_, wv.w, accA[eg*4+3]);
                accB[eg*4+0] = fmaf(xb_, wv.x, accB[eg*4+0]);
                accB[eg*4+1] = fmaf(xb_, wv.y, accB[eg*4+1]);
                accB[eg*4+2] = fmaf(xb_, wv.z, accB[eg*4+2]);
                accB[eg*4+3] = fmaf(xb_, wv.w, accB[eg*4+3]);
            }
        }

        a0=na0; a1=na1; a2=na2; a3=na3;
        b0=nb0; b1=nb1; b2=nb2; b3=nb3;
    }

    if (uwid != 0) {
#pragma unroll
        for (int e = 0; e < NE; ++e) {
            red[uwid - 1][0][lane][e] = accA[e];
            red[uwid - 1][1][lane][e] = accB[e];
        }
    }
    __syncthreads();
    if (uwid != 0) return;

#pragma unroll
    for (int t = 0; t < 2; ++t) {
        double tot[NE];
#pragma unroll
        for (int e = 0; e < NE; ++e) {
            float a = (t == 0) ? accA[e] : accB[e];
            tot[e] = (((double)a + (double)red[0][t][lane][e])
                      + (double)red[1][t][lane][e]) + (double)red[2][t][lane][e];
        }
        RouteR r = route_epilogue(tot, w1b, rbias);
        long tok = (t == 0) ? tokA : tokB;

        double mmin = fmin(r.mg, fmin(r.mo, r.ms));
        if (mmin < MARGIN) {
            int idx = atomicAdd(fcount, 1);
            if (idx < n_tokens) flist[idx] = (int)tok;
        }
        float2 vv; vv.x = (float)r.v1; vv.y = (float)r.v2;
        *(float2*)(dout + tok * 2) = vv;
        float2 iv; iv.x = (float)r.i1; iv.y = (float)r.i2;
        *(float2*)(dout + (long)n_tokens * 2 + tok * 2) = iv;
    }
}

// K2: authoritative fp64 recompute of flagged tokens (cooperative per block)
__global__ __launch_bounds__(256)
void k2_recheck(const float* __restrict__ x,
                const float* __restrict__ wt,
                const float* __restrict__ w1b,
                const float* __restrict__ rbias,
                float* __restrict__ dout,
                const int* __restrict__ fcount,
                const int* __restrict__ flist,
                int n_tokens, int dim)
{
    __shared__ double sred[256][NE];   // 32 KB
    __shared__ double stot[NE];
    const int tid = threadIdx.x;
    int nf = *fcount;
    if (nf > n_tokens) nf = n_tokens;
    const int kpt = dim / 256;         // 16

    for (int i = blockIdx.x; i < nf; i += gridDim.x) {
        const int t = flist[i];
        const float* xr = x + (size_t)t * dim + tid * kpt;

        double part[NE];
#pragma unroll
        for (int e = 0; e < NE; ++e) part[e] = 0.0;
        float xv[16];
#pragma unroll
        for (int q = 0; q < 4; ++q) {
            float4 v = *(const float4*)(xr + q * 4);
            xv[q*4+0]=v.x; xv[q*4+1]=v.y; xv[q*4+2]=v.z; xv[q*4+3]=v.w;
        }
#pragma unroll
        for (int j = 0; j < 16; ++j) {
            double xd = (double)xv[j];
            const float* wr = wt + (size_t)(tid * kpt + j) * NE;
#pragma unroll
            for (int e = 0; e < NE; ++e)
                part[e] = fma(xd, (double)wr[e], part[e]);
        }
#pragma unroll
        for (int e = 0; e < NE; ++e) sred[tid][e] = part[e];
        __syncthreads();

        if (tid < NE) {
            double s = 0.0;
            for (int j = 0; j < 256; ++j) s += sred[j][tid];
            stot[tid] = s;
        }
        __syncthreads();

        if (tid == 0) {
            double tot[NE];
#pragma unroll
            for (int e = 0; e < NE; ++e) tot[e] = stot[e];
            RouteR r = route_epilogue(tot, w1b, rbias);
            float2 vv; vv.x = (float)r.v1; vv.y = (float)r.v2;
            *(float2*)(dout + (long)t * 2) = vv;
            float2 iv; iv.x = (float)r.i1; iv.y = (float)r.i2;
            *(float2*)(dout + (long)n_tokens * 2 + (long)t * 2) = iv;
        }
        __syncthreads();
    }
}

// ---------------- fallback (round-9 proven fp64 structure, w gathered) ------
__global__ __launch_bounds__(256)
void router_fallback(const float* __restrict__ x,
                     const float* __restrict__ w1w,
                     const float* __restrict__ w1b,
                     const float* __restrict__ rbias,
                     float* __restrict__ dout,
                     int n_tokens, int dim)
{
    __shared__ double wbuf4[4][16][NE];
    const int tid  = threadIdx.x;
    const int uwid = __builtin_amdgcn_readfirstlane(tid >> 6);
    const int lane = tid & 63;
    const int slice = dim / 4;
    const int nst  = slice / 16;
    const long tokA = (long)blockIdx.x * 128 + lane;
    const long tokB = tokA + 64;
    const float* xA = x + tokA * (size_t)dim + (size_t)uwid * slice;
    const float* xB = x + tokB * (size_t)dim + (size_t)uwid * slice;

    double accA[NE], accB[NE];
#pragma unroll
    for (int e = 0; e < NE; ++e) { accA[e] = 0.0; accB[e] = 0.0; }

    float4 a0 = *(const float4*)(xA + 0), a1 = *(const float4*)(xA + 4);
    float4 a2 = *(const float4*)(xA + 8), a3 = *(const float4*)(xA + 12);
    float4 b0 = *(const float4*)(xB + 0), b1 = *(const float4*)(xB + 4);
    float4 b2 = *(const float4*)(xB + 8), b3 = *(const float4*)(xB + 12);
    float4 wreg;
    {
        const int i0 = lane * 4;
#pragma unroll
        for (int j = 0; j < 4; ++j) {
            int i = i0 + j;
            ((float*)&wreg)[j] = w1w[(size_t)(i & 15) * dim + uwid * slice + (i >> 4)];
        }
    }

    for (int c = 0; c < nst; ++c) {
        {
            double* dst = &wbuf4[uwid][0][0] + lane * 4;
            dst[0] = (double)wreg.x;  dst[1] = (double)wreg.y;
            dst[2] = (double)wreg.z;  dst[3] = (double)wreg.w;
        }
        float4 na0=a0,na1=a1,na2=a2,na3=a3,nb0=b0,nb1=b1,nb2=b2,nb3=b3;
        if (c + 1 < nst) {
            const float* pa = xA + (c + 1) * 16;
            const float* pb = xB + (c + 1) * 16;
            na0 = *(const float4*)(pa + 0);  na1 = *(const float4*)(pa + 4);
            na2 = *(const float4*)(pa + 8);  na3 = *(const float4*)(pa + 12);
            nb0 = *(const float4*)(pb + 0);  nb1 = *(const float4*)(pb + 4);
            nb2 = *(const float4*)(pb + 8);  nb3 = *(const float4*)(pb + 12);
            const int kb = uwid * slice + (c + 1) * 16;
            const int i0 = lane * 4;
#pragma unroll
            for (int j = 0; j < 4; ++j) {
                int i = i0 + j;
                ((float*)&wreg)[j] = w1w[(size_t)(i & 15) * dim + kb + (i >> 4)];
            }
        }
        float fa[16], fb[16];
        fa[0]=a0.x; fa[1]=a0.y; fa[2]=a0.z; fa[3]=a0.w;
        fa[4]=a1.x; fa[5]=a1.y; fa[6]=a1.z; fa[7]=a1.w;
        fa[8]=a2.x; fa[9]=a2.y; fa[10]=a2.z; fa[11]=a2.w;
        fa[12]=a3.x; fa[13]=a3.y; fa[14]=a3.z; fa[15]=a3.w;
        fb[0]=b0.x; fb[1]=b0.y; fb[2]=b0.z; fb[3]=b0.w;
        fb[4]=b1.x; fb[5]=b1.y; fb[6]=b1.z; fb[7]=b1.w;
        fb[8]=b2.x; fb[9]=b2.y; fb[10]=b2.z; fb[11]=b2.w;
        fb[12]=b3.x; fb[13]=b3.y; fb[14]=b3.z; fb[15]=b3.w;
#pragma unroll
        for (int kk = 0; kk < 16; ++kk) {
            double xa_ = (double)fa[kk];
            double xb_ = (double)fb[kk];
#pragma unroll
            for (int ep = 0; ep < NE / 2; ++ep) {
                double2 wv = *(const double2*)&wbuf4[uwid][kk][ep * 2];
                accA[ep*2+0] = fma(xa_, wv.x, accA[ep*2+0]);
                accA[ep*2+1] = fma(xa_, wv.y, accA[ep*2+1]);
                accB[ep*2+0] = fma(xb_, wv.x, accB[ep*2+0]);
                accB[ep*2+1] = fma(xb_, wv.y, accB[ep*2+1]);
            }
        }
        a0=na0; a1=na1; a2=na2; a3=na3;
        b0=nb0; b1=nb1; b2=nb2; b3=nb3;
    }

    __syncthreads();
    __shared__ double red[3][2][64][NE + 1];
    if (uwid != 0) {
#pragma unroll
        for (int e = 0; e < NE; ++e) {
            red[uwid - 1][0][lane][e] = accA[e];
            red[uwid - 1][1][lane][e] = accB[e];
        }
    }
    __syncthreads();
    if (uwid != 0) return;

#pragma unroll
    for (int t = 0; t < 2; ++t) {
        double tot[NE];
#pragma unroll
        for (int e = 0; e < NE; ++e) {
            double a = (t == 0) ? accA[e] : accB[e];
            tot[e] = ((a + red[0][t][lane][e]) + red[1][t][lane][e])
                     + red[2][t][lane][e];
        }
        RouteR r = route_epilogue(tot, w1b, rbias);
        long tok = (t == 0) ? tokA : tokB;
        float2 vv; vv.x = (float)r.v1; vv.y = (float)r.v2;
        *(float2*)(dout + tok * 2) = vv;
        float2 iv; iv.x = (float)r.i1; iv.y = (float)r.i2;
        *(float2*)(dout + (long)n_tokens * 2 + tok * 2) = iv;
    }
}

extern "C" void kernel_launch(void* const* d_in, const int* in_sizes, int n_in,
                              void* d_out, int out_size, void* d_ws, size_t ws_size,
                              hipStream_t stream)
{
    const float* x   = (const float*)d_in[0];
    const float* w1w = (const float*)d_in[1];
    const float* w1b = (const float*)d_in[2];
    const float* rb  = (const float*)d_in[3];
    float* out = (float*)d_out;

    const int ne       = in_sizes[2];            // 16
    const int dim      = in_sizes[1] / ne;       // 4096
    const int n_tokens = in_sizes[0] / dim;      // 65536

    const int nW = dim * ne;                     // 65536 w elements
    const size_t WT_BYTES  = (size_t)nW * sizeof(float);       // 256 KB
    const size_t COUNT_OFF = WT_BYTES;
    const size_t LIST_OFF  = WT_BYTES + 128;
    const size_t need = LIST_OFF + (size_t)n_tokens * sizeof(int);

    if (ws_size >= need) {
        float* wt    = (float*)d_ws;
        int* fcount  = (int*)((char*)d_ws + COUNT_OFF);
        int* flist   = (int*)((char*)d_ws + LIST_OFF);

        hipMemsetAsync(fcount, 0, sizeof(int), stream);
        hipLaunchKernelGGL(w_transpose_kernel, dim3((nW + 255) / 256), dim3(256),
                           0, stream, w1w, wt, dim, nW);
        hipLaunchKernelGGL(k1_main, dim3(n_tokens / TPB), dim3(NSL * 64),
                           0, stream, x, wt, w1b, rb, out, fcount, flist,
                           n_tokens, dim);
        hipLaunchKernelGGL(k2_recheck, dim3(128), dim3(256),
                           0, stream, x, wt, w1b, rb, out, fcount, flist,
                           n_tokens, dim);
    } else {
        hipLaunchKernelGGL(router_fallback, dim3(n_tokens / 128), dim3(256),
                           0, stream, x, w1w, w1b, rb, out, n_tokens, dim);
    }
}

// Round 12
// 314.854 us; speedup vs baseline: 1.5946x; 1.5609x over previous
//
#include <hip/hip_runtime.h>
#include <math.h>

constexpr int NE  = 16;   // experts
constexpr int NG  = 4;    // groups
constexpr int NSL = 4;    // k-slices = waves per block (K1)
constexpr int KS  = 16;   // k per step
constexpr int TPB = 128;  // tokens per K1 block (2 per lane)
#define MARGIN 1e-4

__global__ __launch_bounds__(256)
void w_transpose_kernel(const float* __restrict__ w, float* __restrict__ wt,
                        int dim, int n) {
    int id = blockIdx.x * 256 + threadIdx.x;
    if (id < n) {
        int k = id / NE;
        int e = id - k * NE;
        wt[id] = w[(size_t)e * dim + k];   // [k][e] fp32
    }
}

struct RouteR { double v1, v2; int i1, i2; double mg, mo, ms; };

// fp64 epilogue from logit totals; also returns ranking margins
__device__ __forceinline__ RouteR route_epilogue(const double* tot,
                                                 const float* w1b,
                                                 const float* rbias)
{
    double logit[NE];
    double m = -INFINITY;
#pragma unroll
    for (int e = 0; e < NE; ++e) {
        logit[e] = tot[e] + (double)w1b[e];
        m = fmax(m, logit[e]);
    }
    double ssum = 0.0, p[NE];
#pragma unroll
    for (int e = 0; e < NE; ++e) { p[e] = exp(logit[e] - m); ssum += p[e]; }
    double inv = 1.0 / ssum, sc[NE];
#pragma unroll
    for (int e = 0; e < NE; ++e) sc[e] = p[e] * inv + (double)rbias[e];

    double gm[NG];
#pragma unroll
    for (int g = 0; g < NG; ++g) {
        double a = fmax(sc[g * 4 + 0], sc[g * 4 + 1]);
        double b = fmax(sc[g * 4 + 2], sc[g * 4 + 3]);
        gm[g] = fmax(a, b);
    }
    int g1 = 0;
#pragma unroll
    for (int g = 1; g < NG; ++g) if (gm[g] > gm[g1]) g1 = g;
    int g2 = (g1 == 0) ? 1 : 0;
#pragma unroll
    for (int g = 0; g < NG; ++g) if (g != g1 && gm[g] > gm[g2]) g2 = g;
    double gm3 = -INFINITY;
#pragma unroll
    for (int g = 0; g < NG; ++g)
        if (g != g1 && g != g2 && gm[g] > gm3) gm3 = gm[g];

    RouteR r;
    r.v1 = -INFINITY; r.i1 = 0;
#pragma unroll
    for (int e = 0; e < NE; ++e) {
        int g = e >> 2;
        bool keep = (g == g1) || (g == g2);
        if (keep && sc[e] > r.v1) { r.v1 = sc[e]; r.i1 = e; }
    }
    r.v2 = -INFINITY; r.i2 = 0;
#pragma unroll
    for (int e = 0; e < NE; ++e) {
        int g = e >> 2;
        bool keep = ((g == g1) || (g == g2)) && (e != r.i1);
        if (keep && sc[e] > r.v2) { r.v2 = sc[e]; r.i2 = e; }
    }
    double v3 = -INFINITY;
#pragma unroll
    for (int e = 0; e < NE; ++e) {
        int g = e >> 2;
        bool keep = ((g == g1) || (g == g2)) && (e != r.i1) && (e != r.i2);
        if (keep && sc[e] > v3) v3 = sc[e];
    }
    r.mg = gm[g2] - gm3;   // group-selection margin (2nd vs 3rd group)
    r.mo = r.v1 - r.v2;    // top1/top2 order margin
    r.ms = r.v2 - v3;      // top2-selection margin
    return r;
}

// K1: fp32 main pass; flags near-ties for fp64 recheck
__global__ __launch_bounds__(256)
void k1_main(const float* __restrict__ x,
             const float* __restrict__ wt,
             const float* __restrict__ w1b,
             const float* __restrict__ rbias,
             float* __restrict__ dout,
             int* __restrict__ fcount,
             int* __restrict__ flist,
             int n_tokens, int dim)
{
    __shared__ float wbuf[NSL][KS][NE];           // 4 KB
    __shared__ float red[NSL - 1][2][64][NE + 1]; // 26112 B

    const int tid  = threadIdx.x;
    const int uwid = __builtin_amdgcn_readfirstlane(tid >> 6);
    const int lane = tid & 63;
    const int slice = dim / NSL;          // 1024
    const int nst  = slice / KS;          // 64
    const long tokA = (long)blockIdx.x * TPB + lane;
    const long tokB = tokA + 64;

    const float* xA = x + tokA * (size_t)dim + (size_t)uwid * slice;
    const float* xB = x + tokB * (size_t)dim + (size_t)uwid * slice;
    const float* wp = wt + (size_t)uwid * slice * NE;

    float accA[NE], accB[NE];
#pragma unroll
    for (int e = 0; e < NE; ++e) { accA[e] = 0.f; accB[e] = 0.f; }

    float4 a0 = *(const float4*)(xA + 0),  a1 = *(const float4*)(xA + 4);
    float4 a2 = *(const float4*)(xA + 8),  a3 = *(const float4*)(xA + 12);
    float4 b0 = *(const float4*)(xB + 0),  b1 = *(const float4*)(xB + 4);
    float4 b2 = *(const float4*)(xB + 8),  b3 = *(const float4*)(xB + 12);
    float4 wreg = *(const float4*)(wp + lane * 4);

    for (int c = 0; c < nst; ++c) {
        ((float4*)&wbuf[uwid][0][0])[lane] = wreg;

        float4 na0 = a0, na1 = a1, na2 = a2, na3 = a3;
        float4 nb0 = b0, nb1 = b1, nb2 = b2, nb3 = b3;
        if (c + 1 < nst) {
            const float* pa = xA + (c + 1) * KS;
            const float* pb = xB + (c + 1) * KS;
            na0 = *(const float4*)(pa + 0);  na1 = *(const float4*)(pa + 4);
            na2 = *(const float4*)(pa + 8);  na3 = *(const float4*)(pa + 12);
            nb0 = *(const float4*)(pb + 0);  nb1 = *(const float4*)(pb + 4);
            nb2 = *(const float4*)(pb + 8);  nb3 = *(const float4*)(pb + 12);
            wreg = *(const float4*)(wp + (size_t)(c + 1) * KS * NE + lane * 4);
        }

        float fa[KS], fb[KS];
        fa[0]=a0.x;  fa[1]=a0.y;  fa[2]=a0.z;  fa[3]=a0.w;
        fa[4]=a1.x;  fa[5]=a1.y;  fa[6]=a1.z;  fa[7]=a1.w;
        fa[8]=a2.x;  fa[9]=a2.y;  fa[10]=a2.z; fa[11]=a2.w;
        fa[12]=a3.x; fa[13]=a3.y; fa[14]=a3.z; fa[15]=a3.w;
        fb[0]=b0.x;  fb[1]=b0.y;  fb[2]=b0.z;  fb[3]=b0.w;
        fb[4]=b1.x;  fb[5]=b1.y;  fb[6]=b1.z;  fb[7]=b1.w;
        fb[8]=b2.x;  fb[9]=b2.y;  fb[10]=b2.z; fb[11]=b2.w;
        fb[12]=b3.x; fb[13]=b3.y; fb[14]=b3.z; fb[15]=b3.w;

#pragma unroll
        for (int kk = 0; kk < KS; ++kk) {
            float xa_ = fa[kk];
            float xb_ = fb[kk];
#pragma unroll
            for (int eg = 0; eg < 4; ++eg) {
                float4 wv = *(const float4*)&wbuf[uwid][kk][eg * 4];
                accA[eg*4+0] = fmaf(xa_, wv.x, accA[eg*4+0]);
                accA[eg*4+1] = fmaf(xa_, wv.y, accA[eg*4+1]);
                accA[eg*4+2] = fmaf(xa_, wv.z, accA[eg*4+2]);
                accA[eg*4+3] = fmaf(xa_, wv.w, accA[eg*4+3]);
                accB[eg*4+0] = fmaf(xb_, wv.x, accB[eg*4+0]);
                accB[eg*4+1] = fmaf(xb_, wv.y, accB[eg*4+1]);
                accB[eg*4+2] = fmaf(xb_, wv.z, accB[eg*4+2]);
                accB[eg*4+3] = fmaf(xb_, wv.w, accB[eg*4+3]);
            }
        }

        a0=na0; a1=na1; a2=na2; a3=na3;
        b0=nb0; b1=nb1; b2=nb2; b3=nb3;
    }

    if (uwid != 0) {
#pragma unroll
        for (int e = 0; e < NE; ++e) {
            red[uwid - 1][0][lane][e] = accA[e];
            red[uwid - 1][1][lane][e] = accB[e];
        }
    }
    __syncthreads();
    if (uwid != 0) return;

#pragma unroll
    for (int t = 0; t < 2; ++t) {
        double tot[NE];
#pragma unroll
        for (int e = 0; e < NE; ++e) {
            float a = (t == 0) ? accA[e] : accB[e];
            tot[e] = (((double)a + (double)red[0][t][lane][e])
                      + (double)red[1][t][lane][e]) + (double)red[2][t][lane][e];
        }
        RouteR r = route_epilogue(tot, w1b, rbias);
        long tok = (t == 0) ? tokA : tokB;

        double mmin = fmin(r.mg, fmin(r.mo, r.ms));
        if (mmin < MARGIN) {
            int idx = atomicAdd(fcount, 1);
            if (idx < n_tokens) flist[idx] = (int)tok;
        }
        float2 vv; vv.x = (float)r.v1; vv.y = (float)r.v2;
        *(float2*)(dout + tok * 2) = vv;
        float2 iv; iv.x = (float)r.i1; iv.y = (float)r.i2;
        *(float2*)(dout + (long)n_tokens * 2 + tok * 2) = iv;
    }
}

// K2: authoritative fp64 recompute, ONE WAVE PER FLAGGED TOKEN.
// Coalesced x loads (k = q*256 + lane*4 + j), register partials,
// 6-level shuffle butterfly, no LDS, no barriers.
__global__ __launch_bounds__(256)
void k2_recheck(const float* __restrict__ x,
                const float* __restrict__ wt,
                const float* __restrict__ w1b,
                const float* __restrict__ rbias,
                float* __restrict__ dout,
                const int* __restrict__ fcount,
                const int* __restrict__ flist,
                int n_tokens, int dim)
{
    const int tid  = threadIdx.x;
    const int lane = tid & 63;
    const int wavesPerBlock = blockDim.x >> 6;
    const int wglobal = blockIdx.x * wavesPerBlock + (tid >> 6);
    const int nwaves  = gridDim.x * wavesPerBlock;
    int nf = *fcount;
    if (nf > n_tokens) nf = n_tokens;
    const int nq = dim / 256;   // 16

    for (int i = wglobal; i < nf; i += nwaves) {
        const int t = flist[i];
        const float* xr = x + (size_t)t * dim;

        double part[NE];
#pragma unroll
        for (int e = 0; e < NE; ++e) part[e] = 0.0;

        for (int q = 0; q < nq; ++q) {
            float4 xv = *(const float4*)(xr + q * 256 + lane * 4);
#pragma unroll
            for (int j = 0; j < 4; ++j) {
                int k = q * 256 + lane * 4 + j;
                double xd = (double)((const float*)&xv)[j];
                const float* wr = wt + (size_t)k * NE;
#pragma unroll
                for (int e = 0; e < NE; ++e)
                    part[e] = fma(xd, (double)wr[e], part[e]);
            }
        }

        // butterfly reduction across 64 lanes (fixed order -> deterministic)
#pragma unroll
        for (int off = 1; off < 64; off <<= 1) {
#pragma unroll
            for (int e = 0; e < NE; ++e)
                part[e] += __shfl_xor(part[e], off, 64);
        }

        RouteR r = route_epilogue(part, w1b, rbias);
        if (lane == 0) {
            float2 vv; vv.x = (float)r.v1; vv.y = (float)r.v2;
            *(float2*)(dout + (long)t * 2) = vv;
            float2 iv; iv.x = (float)r.i1; iv.y = (float)r.i2;
            *(float2*)(dout + (long)n_tokens * 2 + (long)t * 2) = iv;
        }
    }
}

// ---------------- fallback (round-9 proven fp64 structure, w gathered) ------
__global__ __launch_bounds__(256)
void router_fallback(const float* __restrict__ x,
                     const float* __restrict__ w1w,
                     const float* __restrict__ w1b,
                     const float* __restrict__ rbias,
                     float* __restrict__ dout,
                     int n_tokens, int dim)
{
    __shared__ double wbuf4[4][16][NE];
    const int tid  = threadIdx.x;
    const int uwid = __builtin_amdgcn_readfirstlane(tid >> 6);
    const int lane = tid & 63;
    const int slice = dim / 4;
    const int nst  = slice / 16;
    const long tokA = (long)blockIdx.x * 128 + lane;
    const long tokB = tokA + 64;
    const float* xA = x + tokA * (size_t)dim + (size_t)uwid * slice;
    const float* xB = x + tokB * (size_t)dim + (size_t)uwid * slice;

    double accA[NE], accB[NE];
#pragma unroll
    for (int e = 0; e < NE; ++e) { accA[e] = 0.0; accB[e] = 0.0; }

    float4 a0 = *(const float4*)(xA + 0), a1 = *(const float4*)(xA + 4);
    float4 a2 = *(const float4*)(xA + 8), a3 = *(const float4*)(xA + 12);
    float4 b0 = *(const float4*)(xB + 0), b1 = *(const float4*)(xB + 4);
    float4 b2 = *(const float4*)(xB + 8), b3 = *(const float4*)(xB + 12);
    float4 wreg;
    {
        const int i0 = lane * 4;
#pragma unroll
        for (int j = 0; j < 4; ++j) {
            int i = i0 + j;
            ((float*)&wreg)[j] = w1w[(size_t)(i & 15) * dim + uwid * slice + (i >> 4)];
        }
    }

    for (int c = 0; c < nst; ++c) {
        {
            double* dst = &wbuf4[uwid][0][0] + lane * 4;
            dst[0] = (double)wreg.x;  dst[1] = (double)wreg.y;
            dst[2] = (double)wreg.z;  dst[3] = (double)wreg.w;
        }
        float4 na0=a0,na1=a1,na2=a2,na3=a3,nb0=b0,nb1=b1,nb2=b2,nb3=b3;
        if (c + 1 < nst) {
            const float* pa = xA + (c + 1) * 16;
            const float* pb = xB + (c + 1) * 16;
            na0 = *(const float4*)(pa + 0);  na1 = *(const float4*)(pa + 4);
            na2 = *(const float4*)(pa + 8);  na3 = *(const float4*)(pa + 12);
            nb0 = *(const float4*)(pb + 0);  nb1 = *(const float4*)(pb + 4);
            nb2 = *(const float4*)(pb + 8);  nb3 = *(const float4*)(pb + 12);
            const int kb = uwid * slice + (c + 1) * 16;
            const int i0 = lane * 4;
#pragma unroll
            for (int j = 0; j < 4; ++j) {
                int i = i0 + j;
                ((float*)&wreg)[j] = w1w[(size_t)(i & 15) * dim + kb + (i >> 4)];
            }
        }
        float fa[16], fb[16];
        fa[0]=a0.x; fa[1]=a0.y; fa[2]=a0.z; fa[3]=a0.w;
        fa[4]=a1.x; fa[5]=a1.y; fa[6]=a1.z; fa[7]=a1.w;
        fa[8]=a2.x; fa[9]=a2.y; fa[10]=a2.z; fa[11]=a2.w;
        fa[12]=a3.x; fa[13]=a3.y; fa[14]=a3.z; fa[15]=a3.w;
        fb[0]=b0.x; fb[1]=b0.y; fb[2]=b0.z; fb[3]=b0.w;
        fb[4]=b1.x; fb[5]=b1.y; fb[6]=b1.z; fb[7]=b1.w;
        fb[8]=b2.x; fb[9]=b2.y; fb[10]=b2.z; fb[11]=b2.w;
        fb[12]=b3.x; fb[13]=b3.y; fb[14]=b3.z; fb[15]=b3.w;
#pragma unroll
        for (int kk = 0; kk < 16; ++kk) {
            double xa_ = (double)fa[kk];
            double xb_ = (double)fb[kk];
#pragma unroll
            for (int ep = 0; ep < NE / 2; ++ep) {
                double2 wv = *(const double2*)&wbuf4[uwid][kk][ep * 2];
                accA[ep*2+0] = fma(xa_, wv.x, accA[ep*2+0]);
                accA[ep*2+1] = fma(xa_, wv.y, accA[ep*2+1]);
                accB[ep*2+0] = fma(xb_, wv.x, accB[ep*2+0]);
                accB[ep*2+1] = fma(xb_, wv.y, accB[ep*2+1]);
            }
        }
        a0=na0; a1=na1; a2=na2; a3=na3;
        b0=nb0; b1=nb1; b2=nb2; b3=nb3;
    }

    __syncthreads();
    __shared__ double red[3][2][64][NE + 1];
    if (uwid != 0) {
#pragma unroll
        for (int e = 0; e < NE; ++e) {
            red[uwid - 1][0][lane][e] = accA[e];
            red[uwid - 1][1][lane][e] = accB[e];
        }
    }
    __syncthreads();
    if (uwid != 0) return;

#pragma unroll
    for (int t = 0; t < 2; ++t) {
        double tot[NE];
#pragma unroll
        for (int e = 0; e < NE; ++e) {
            double a = (t == 0) ? accA[e] : accB[e];
            tot[e] = ((a + red[0][t][lane][e]) + red[1][t][lane][e])
                     + red[2][t][lane][e];
        }
        RouteR r = route_epilogue(tot, w1b, rbias);
        long tok = (t == 0) ? tokA : tokB;
        float2 vv; vv.x = (float)r.v1; vv.y = (float)r.v2;
        *(float2*)(dout + tok * 2) = vv;
        float2 iv; iv.x = (float)r.i1; iv.y = (float)r.i2;
        *(float2*)(dout + (long)n_tokens * 2 + tok * 2) = iv;
    }
}

extern "C" void kernel_launch(void* const* d_in, const int* in_sizes, int n_in,
                              void* d_out, int out_size, void* d_ws, size_t ws_size,
                              hipStream_t stream)
{
    const float* x   = (const float*)d_in[0];
    const float* w1w = (const float*)d_in[1];
    const float* w1b = (const float*)d_in[2];
    const float* rb  = (const float*)d_in[3];
    float* out = (float*)d_out;

    const int ne       = in_sizes[2];            // 16
    const int dim      = in_sizes[1] / ne;       // 4096
    const int n_tokens = in_sizes[0] / dim;      // 65536

    const int nW = dim * ne;                     // 65536 w elements
    const size_t WT_BYTES  = (size_t)nW * sizeof(float);       // 256 KB
    const size_t COUNT_OFF = WT_BYTES;
    const size_t LIST_OFF  = WT_BYTES + 128;
    const size_t need = LIST_OFF + (size_t)n_tokens * sizeof(int);

    if (ws_size >= need) {
        float* wt    = (float*)d_ws;
        int* fcount  = (int*)((char*)d_ws + COUNT_OFF);
        int* flist   = (int*)((char*)d_ws + LIST_OFF);

        hipMemsetAsync(fcount, 0, sizeof(int), stream);
        hipLaunchKernelGGL(w_transpose_kernel, dim3((nW + 255) / 256), dim3(256),
                           0, stream, w1w, wt, dim, nW);
        hipLaunchKernelGGL(k1_main, dim3(n_tokens / TPB), dim3(NSL * 64),
                           0, stream, x, wt, w1b, rb, out, fcount, flist,
                           n_tokens, dim);
        hipLaunchKernelGGL(k2_recheck, dim3(256), dim3(256),
                           0, stream, x, wt, w1b, rb, out, fcount, flist,
                           n_tokens, dim);
    } else {
        hipLaunchKernelGGL(router_fallback, dim3(n_tokens / 128), dim3(256),
                           0, stream, x, w1w, w1b, rb, out, n_tokens, dim);
    }
}

// Round 13
// 306.093 us; speedup vs baseline: 1.6403x; 1.0286x over previous
//
#include <hip/hip_runtime.h>
#include <math.h>

constexpr int NE  = 16;   // experts
constexpr int NG  = 4;    // groups
constexpr int NSL = 8;    // k-slices = waves per block (K1)
constexpr int KS  = 16;   // k per step
constexpr int TPB = 128;  // tokens per K1 block (2 per lane)
#define MARGIN 1e-4

__global__ __launch_bounds__(256)
void w_transpose_kernel(const float* __restrict__ w, float* __restrict__ wt,
                        int dim, int n) {
    int id = blockIdx.x * 256 + threadIdx.x;
    if (id < n) {
        int k = id / NE;
        int e = id - k * NE;
        wt[id] = w[(size_t)e * dim + k];   // [k][e] fp32
    }
}

struct RouteR { double v1, v2; int i1, i2; double mg, mo, ms; };

// fp64 epilogue from logit totals; also returns ranking margins
__device__ __forceinline__ RouteR route_epilogue(const double* tot,
                                                 const float* w1b,
                                                 const float* rbias)
{
    double logit[NE];
    double m = -INFINITY;
#pragma unroll
    for (int e = 0; e < NE; ++e) {
        logit[e] = tot[e] + (double)w1b[e];
        m = fmax(m, logit[e]);
    }
    double ssum = 0.0, p[NE];
#pragma unroll
    for (int e = 0; e < NE; ++e) { p[e] = exp(logit[e] - m); ssum += p[e]; }
    double inv = 1.0 / ssum, sc[NE];
#pragma unroll
    for (int e = 0; e < NE; ++e) sc[e] = p[e] * inv + (double)rbias[e];

    double gm[NG];
#pragma unroll
    for (int g = 0; g < NG; ++g) {
        double a = fmax(sc[g * 4 + 0], sc[g * 4 + 1]);
        double b = fmax(sc[g * 4 + 2], sc[g * 4 + 3]);
        gm[g] = fmax(a, b);
    }
    int g1 = 0;
#pragma unroll
    for (int g = 1; g < NG; ++g) if (gm[g] > gm[g1]) g1 = g;
    int g2 = (g1 == 0) ? 1 : 0;
#pragma unroll
    for (int g = 0; g < NG; ++g) if (g != g1 && gm[g] > gm[g2]) g2 = g;
    double gm3 = -INFINITY;
#pragma unroll
    for (int g = 0; g < NG; ++g)
        if (g != g1 && g != g2 && gm[g] > gm3) gm3 = gm[g];

    RouteR r;
    r.v1 = -INFINITY; r.i1 = 0;
#pragma unroll
    for (int e = 0; e < NE; ++e) {
        int g = e >> 2;
        bool keep = (g == g1) || (g == g2);
        if (keep && sc[e] > r.v1) { r.v1 = sc[e]; r.i1 = e; }
    }
    r.v2 = -INFINITY; r.i2 = 0;
#pragma unroll
    for (int e = 0; e < NE; ++e) {
        int g = e >> 2;
        bool keep = ((g == g1) || (g == g2)) && (e != r.i1);
        if (keep && sc[e] > r.v2) { r.v2 = sc[e]; r.i2 = e; }
    }
    double v3 = -INFINITY;
#pragma unroll
    for (int e = 0; e < NE; ++e) {
        int g = e >> 2;
        bool keep = ((g == g1) || (g == g2)) && (e != r.i1) && (e != r.i2);
        if (keep && sc[e] > v3) v3 = sc[e];
    }
    r.mg = gm[g2] - gm3;   // group-selection margin (2nd vs 3rd group)
    r.mo = r.v1 - r.v2;    // top1/top2 order margin
    r.ms = r.v2 - v3;      // top2-selection margin
    return r;
}

// K1: fp32 main pass, 8 k-slice waves (4 waves/SIMD); flags near-ties
__global__ __launch_bounds__(512)
void k1_main(const float* __restrict__ x,
             const float* __restrict__ wt,
             const float* __restrict__ w1b,
             const float* __restrict__ rbias,
             float* __restrict__ dout,
             int* __restrict__ fcount,
             int* __restrict__ flist,
             int n_tokens, int dim)
{
    __shared__ float wbuf[NSL][KS][NE];           // 16 KB
    __shared__ float red[NSL - 1][2][64][NE + 1]; // 60928 B

    const int tid  = threadIdx.x;
    const int uwid = __builtin_amdgcn_readfirstlane(tid >> 6);
    const int lane = tid & 63;
    const int slice = dim / NSL;          // 512
    const int nst  = slice / KS;          // 32
    const long tokA = (long)blockIdx.x * TPB + lane;
    const long tokB = tokA + 64;

    const float* xA = x + tokA * (size_t)dim + (size_t)uwid * slice;
    const float* xB = x + tokB * (size_t)dim + (size_t)uwid * slice;
    const float* wp = wt + (size_t)uwid * slice * NE;

    float accA[NE], accB[NE];
#pragma unroll
    for (int e = 0; e < NE; ++e) { accA[e] = 0.f; accB[e] = 0.f; }

    float4 a0 = *(const float4*)(xA + 0),  a1 = *(const float4*)(xA + 4);
    float4 a2 = *(const float4*)(xA + 8),  a3 = *(const float4*)(xA + 12);
    float4 b0 = *(const float4*)(xB + 0),  b1 = *(const float4*)(xB + 4);
    float4 b2 = *(const float4*)(xB + 8),  b3 = *(const float4*)(xB + 12);
    float4 wreg = *(const float4*)(wp + lane * 4);

    for (int c = 0; c < nst; ++c) {
        ((float4*)&wbuf[uwid][0][0])[lane] = wreg;

        float4 na0 = a0, na1 = a1, na2 = a2, na3 = a3;
        float4 nb0 = b0, nb1 = b1, nb2 = b2, nb3 = b3;
        if (c + 1 < nst) {
            const float* pa = xA + (c + 1) * KS;
            const float* pb = xB + (c + 1) * KS;
            na0 = *(const float4*)(pa + 0);  na1 = *(const float4*)(pa + 4);
            na2 = *(const float4*)(pa + 8);  na3 = *(const float4*)(pa + 12);
            nb0 = *(const float4*)(pb + 0);  nb1 = *(const float4*)(pb + 4);
            nb2 = *(const float4*)(pb + 8);  nb3 = *(const float4*)(pb + 12);
            wreg = *(const float4*)(wp + (size_t)(c + 1) * KS * NE + lane * 4);
        }

        float fa[KS], fb[KS];
        fa[0]=a0.x;  fa[1]=a0.y;  fa[2]=a0.z;  fa[3]=a0.w;
        fa[4]=a1.x;  fa[5]=a1.y;  fa[6]=a1.z;  fa[7]=a1.w;
        fa[8]=a2.x;  fa[9]=a2.y;  fa[10]=a2.z; fa[11]=a2.w;
        fa[12]=a3.x; fa[13]=a3.y; fa[14]=a3.z; fa[15]=a3.w;
        fb[0]=b0.x;  fb[1]=b0.y;  fb[2]=b0.z;  fb[3]=b0.w;
        fb[4]=b1.x;  fb[5]=b1.y;  fb[6]=b1.z;  fb[7]=b1.w;
        fb[8]=b2.x;  fb[9]=b2.y;  fb[10]=b2.z; fb[11]=b2.w;
        fb[12]=b3.x; fb[13]=b3.y; fb[14]=b3.z; fb[15]=b3.w;

#pragma unroll
        for (int kk = 0; kk < KS; ++kk) {
            float xa_ = fa[kk];
            float xb_ = fb[kk];
#pragma unroll
            for (int eg = 0; eg < 4; ++eg) {
                float4 wv = *(const float4*)&wbuf[uwid][kk][eg * 4];
                accA[eg*4+0] = fmaf(xa_, wv.x, accA[eg*4+0]);
                accA[eg*4+1] = fmaf(xa_, wv.y, accA[eg*4+1]);
                accA[eg*4+2] = fmaf(xa_, wv.z, accA[eg*4+2]);
                accA[eg*4+3] = fmaf(xa_, wv.w, accA[eg*4+3]);
                accB[eg*4+0] = fmaf(xb_, wv.x, accB[eg*4+0]);
                accB[eg*4+1] = fmaf(xb_, wv.y, accB[eg*4+1]);
                accB[eg*4+2] = fmaf(xb_, wv.z, accB[eg*4+2]);
                accB[eg*4+3] = fmaf(xb_, wv.w, accB[eg*4+3]);
            }
        }

        a0=na0; a1=na1; a2=na2; a3=na3;
        b0=nb0; b1=nb1; b2=nb2; b3=nb3;
    }

    if (uwid != 0) {
#pragma unroll
        for (int e = 0; e < NE; ++e) {
            red[uwid - 1][0][lane][e] = accA[e];
            red[uwid - 1][1][lane][e] = accB[e];
        }
    }
    __syncthreads();
    if (uwid != 0) return;

#pragma unroll
    for (int t = 0; t < 2; ++t) {
        double tot[NE];
#pragma unroll
        for (int e = 0; e < NE; ++e) {
            double s = (double)((t == 0) ? accA[e] : accB[e]);
#pragma unroll
            for (int s7 = 0; s7 < NSL - 1; ++s7)
                s += (double)red[s7][t][lane][e];
            tot[e] = s;
        }
        RouteR r = route_epilogue(tot, w1b, rbias);
        long tok = (t == 0) ? tokA : tokB;

        double mmin = fmin(r.mg, fmin(r.mo, r.ms));
        if (mmin < MARGIN) {
            int idx = atomicAdd(fcount, 1);
            if (idx < n_tokens) flist[idx] = (int)tok;
        }
        float2 vv; vv.x = (float)r.v1; vv.y = (float)r.v2;
        *(float2*)(dout + tok * 2) = vv;
        float2 iv; iv.x = (float)r.i1; iv.y = (float)r.i2;
        *(float2*)(dout + (long)n_tokens * 2 + tok * 2) = iv;
    }
}

// K2: authoritative fp64 recompute, one wave per flagged token.
__global__ __launch_bounds__(256)
void k2_recheck(const float* __restrict__ x,
                const float* __restrict__ wt,
                const float* __restrict__ w1b,
                const float* __restrict__ rbias,
                float* __restrict__ dout,
                const int* __restrict__ fcount,
                const int* __restrict__ flist,
                int n_tokens, int dim)
{
    const int tid  = threadIdx.x;
    const int lane = tid & 63;
    const int wavesPerBlock = blockDim.x >> 6;
    const int wglobal = blockIdx.x * wavesPerBlock + (tid >> 6);
    const int nwaves  = gridDim.x * wavesPerBlock;
    int nf = *fcount;
    if (nf > n_tokens) nf = n_tokens;
    const int nq = dim / 256;   // 16

    for (int i = wglobal; i < nf; i += nwaves) {
        const int t = flist[i];
        const float* xr = x + (size_t)t * dim;

        double part[NE];
#pragma unroll
        for (int e = 0; e < NE; ++e) part[e] = 0.0;

        for (int q = 0; q < nq; ++q) {
            float4 xv = *(const float4*)(xr + q * 256 + lane * 4);
#pragma unroll
            for (int j = 0; j < 4; ++j) {
                int k = q * 256 + lane * 4 + j;
                double xd = (double)((const float*)&xv)[j];
                const float* wr = wt + (size_t)k * NE;
#pragma unroll
                for (int e = 0; e < NE; ++e)
                    part[e] = fma(xd, (double)wr[e], part[e]);
            }
        }

#pragma unroll
        for (int off = 1; off < 64; off <<= 1) {
#pragma unroll
            for (int e = 0; e < NE; ++e)
                part[e] += __shfl_xor(part[e], off, 64);
        }

        RouteR r = route_epilogue(part, w1b, rbias);
        if (lane == 0) {
            float2 vv; vv.x = (float)r.v1; vv.y = (float)r.v2;
            *(float2*)(dout + (long)t * 2) = vv;
            float2 iv; iv.x = (float)r.i1; iv.y = (float)r.i2;
            *(float2*)(dout + (long)n_tokens * 2 + (long)t * 2) = iv;
        }
    }
}

// ---------------- fallback (round-9 proven fp64 structure, w gathered) ------
__global__ __launch_bounds__(256)
void router_fallback(const float* __restrict__ x,
                     const float* __restrict__ w1w,
                     const float* __restrict__ w1b,
                     const float* __restrict__ rbias,
                     float* __restrict__ dout,
                     int n_tokens, int dim)
{
    __shared__ double wbuf4[4][16][NE];
    const int tid  = threadIdx.x;
    const int uwid = __builtin_amdgcn_readfirstlane(tid >> 6);
    const int lane = tid & 63;
    const int slice = dim / 4;
    const int nst  = slice / 16;
    const long tokA = (long)blockIdx.x * 128 + lane;
    const long tokB = tokA + 64;
    const float* xA = x + tokA * (size_t)dim + (size_t)uwid * slice;
    const float* xB = x + tokB * (size_t)dim + (size_t)uwid * slice;

    double accA[NE], accB[NE];
#pragma unroll
    for (int e = 0; e < NE; ++e) { accA[e] = 0.0; accB[e] = 0.0; }

    float4 a0 = *(const float4*)(xA + 0), a1 = *(const float4*)(xA + 4);
    float4 a2 = *(const float4*)(xA + 8), a3 = *(const float4*)(xA + 12);
    float4 b0 = *(const float4*)(xB + 0), b1 = *(const float4*)(xB + 4);
    float4 b2 = *(const float4*)(xB + 8), b3 = *(const float4*)(xB + 12);
    float4 wreg;
    {
        const int i0 = lane * 4;
#pragma unroll
        for (int j = 0; j < 4; ++j) {
            int i = i0 + j;
            ((float*)&wreg)[j] = w1w[(size_t)(i & 15) * dim + uwid * slice + (i >> 4)];
        }
    }

    for (int c = 0; c < nst; ++c) {
        {
            double* dst = &wbuf4[uwid][0][0] + lane * 4;
            dst[0] = (double)wreg.x;  dst[1] = (double)wreg.y;
            dst[2] = (double)wreg.z;  dst[3] = (double)wreg.w;
        }
        float4 na0=a0,na1=a1,na2=a2,na3=a3,nb0=b0,nb1=b1,nb2=b2,nb3=b3;
        if (c + 1 < nst) {
            const float* pa = xA + (c + 1) * 16;
            const float* pb = xB + (c + 1) * 16;
            na0 = *(const float4*)(pa + 0);  na1 = *(const float4*)(pa + 4);
            na2 = *(const float4*)(pa + 8);  na3 = *(const float4*)(pa + 12);
            nb0 = *(const float4*)(pb + 0);  nb1 = *(const float4*)(pb + 4);
            nb2 = *(const float4*)(pb + 8);  nb3 = *(const float4*)(pb + 12);
            const int kb = uwid * slice + (c + 1) * 16;
            const int i0 = lane * 4;
#pragma unroll
            for (int j = 0; j < 4; ++j) {
                int i = i0 + j;
                ((float*)&wreg)[j] = w1w[(size_t)(i & 15) * dim + kb + (i >> 4)];
            }
        }
        float fa[16], fb[16];
        fa[0]=a0.x; fa[1]=a0.y; fa[2]=a0.z; fa[3]=a0.w;
        fa[4]=a1.x; fa[5]=a1.y; fa[6]=a1.z; fa[7]=a1.w;
        fa[8]=a2.x; fa[9]=a2.y; fa[10]=a2.z; fa[11]=a2.w;
        fa[12]=a3.x; fa[13]=a3.y; fa[14]=a3.z; fa[15]=a3.w;
        fb[0]=b0.x; fb[1]=b0.y; fb[2]=b0.z; fb[3]=b0.w;
        fb[4]=b1.x; fb[5]=b1.y; fb[6]=b1.z; fb[7]=b1.w;
        fb[8]=b2.x; fb[9]=b2.y; fb[10]=b2.z; fb[11]=b2.w;
        fb[12]=b3.x; fb[13]=b3.y; fb[14]=b3.z; fb[15]=b3.w;
#pragma unroll
        for (int kk = 0; kk < 16; ++kk) {
            double xa_ = (double)fa[kk];
            double xb_ = (double)fb[kk];
#pragma unroll
            for (int ep = 0; ep < NE / 2; ++ep) {
                double2 wv = *(const double2*)&wbuf4[uwid][kk][ep * 2];
                accA[ep*2+0] = fma(xa_, wv.x, accA[ep*2+0]);
                accA[ep*2+1] = fma(xa_, wv.y, accA[ep*2+1]);
                accB[ep*2+0] = fma(xb_, wv.x, accB[ep*2+0]);
                accB[ep*2+1] = fma(xb_, wv.y, accB[ep*2+1]);
            }
        }
        a0=na0; a1=na1; a2=na2; a3=na3;
        b0=nb0; b1=nb1; b2=nb2; b3=nb3;
    }

    __syncthreads();
    __shared__ double red[3][2][64][NE + 1];
    if (uwid != 0) {
#pragma unroll
        for (int e = 0; e < NE; ++e) {
            red[uwid - 1][0][lane][e] = accA[e];
            red[uwid - 1][1][lane][e] = accB[e];
        }
    }
    __syncthreads();
    if (uwid != 0) return;

#pragma unroll
    for (int t = 0; t < 2; ++t) {
        double tot[NE];
#pragma unroll
        for (int e = 0; e < NE; ++e) {
            double a = (t == 0) ? accA[e] : accB[e];
            tot[e] = ((a + red[0][t][lane][e]) + red[1][t][lane][e])
                     + red[2][t][lane][e];
        }
        RouteR r = route_epilogue(tot, w1b, rbias);
        long tok = (t == 0) ? tokA : tokB;
        float2 vv; vv.x = (float)r.v1; vv.y = (float)r.v2;
        *(float2*)(dout + tok * 2) = vv;
        float2 iv; iv.x = (float)r.i1; iv.y = (float)r.i2;
        *(float2*)(dout + (long)n_tokens * 2 + tok * 2) = iv;
    }
}

extern "C" void kernel_launch(void* const* d_in, const int* in_sizes, int n_in,
                              void* d_out, int out_size, void* d_ws, size_t ws_size,
                              hipStream_t stream)
{
    const float* x   = (const float*)d_in[0];
    const float* w1w = (const float*)d_in[1];
    const float* w1b = (const float*)d_in[2];
    const float* rb  = (const float*)d_in[3];
    float* out = (float*)d_out;

    const int ne       = in_sizes[2];            // 16
    const int dim      = in_sizes[1] / ne;       // 4096
    const int n_tokens = in_sizes[0] / dim;      // 65536

    const int nW = dim * ne;                     // 65536 w elements
    const size_t WT_BYTES  = (size_t)nW * sizeof(float);       // 256 KB
    const size_t COUNT_OFF = WT_BYTES;
    const size_t LIST_OFF  = WT_BYTES + 128;
    const size_t need = LIST_OFF + (size_t)n_tokens * sizeof(int);

    if (ws_size >= need) {
        float* wt    = (float*)d_ws;
        int* fcount  = (int*)((char*)d_ws + COUNT_OFF);
        int* flist   = (int*)((char*)d_ws + LIST_OFF);

        hipMemsetAsync(fcount, 0, sizeof(int), stream);
        hipLaunchKernelGGL(w_transpose_kernel, dim3((nW + 255) / 256), dim3(256),
                           0, stream, w1w, wt, dim, nW);
        hipLaunchKernelGGL(k1_main, dim3(n_tokens / TPB), dim3(NSL * 64),
                           0, stream, x, wt, w1b, rb, out, fcount, flist,
                           n_tokens, dim);
        hipLaunchKernelGGL(k2_recheck, dim3(256), dim3(256),
                           0, stream, x, wt, w1b, rb, out, fcount, flist,
                           n_tokens, dim);
    } else {
        hipLaunchKernelGGL(router_fallback, dim3(n_tokens / 128), dim3(256),
                           0, stream, x, w1w, w1b, rb, out, n_tokens, dim);
    }
}